// Round 11
// baseline (154.438 us; speedup 1.0000x reference)
//
#include <hip/hip_runtime.h>
#include <math.h>

#define Hd 128
#define Rr 3
#define Ll 4
#define NPW 16   // nodes (M-rows) per wave
#define NW  4    // waves per block (256 threads); 469 blocks -> ~2 blocks/CU co-resident
#define SRP 136  // Sr row pitch in bf16 elems (272 B: 16-B aligned, bank-benign)

typedef float f32x4 __attribute__((ext_vector_type(4)));
typedef short s16x8 __attribute__((ext_vector_type(8)));

__device__ __forceinline__ unsigned short f2bf(float f){
    unsigned u = __float_as_uint(f);
    return (unsigned short)((u + 0x7FFFu + ((u >> 16) & 1u)) >> 16);
}
__device__ __forceinline__ float bf2f(unsigned short h){
    return __uint_as_float(((unsigned)h) << 16);
}
// convert 8 consecutive f32 (global) -> bf16 A-fragment
__device__ __forceinline__ s16x8 cvt8(const float* p){
    float4 a = *(const float4*)p;
    float4 b = *(const float4*)(p + 4);
    float v[8] = {a.x, a.y, a.z, a.w, b.x, b.y, b.z, b.w};
    s16x8 r;
    #pragma unroll
    for (int j = 0; j < 8; ++j) r[j] = (short)f2bf(v[j]);
    return r;
}
__device__ __forceinline__ int lower_bound_i32(const int* __restrict__ a, int n, int key){
    int lo = 0, hi = n;
    while (lo < hi){
        int mid = (lo + hi) >> 1;
        if (a[mid] < key) lo = mid + 1; else hi = mid;
    }
    return lo;
}

// async global->LDS, 16B per lane; LDS dest = uniform base + lane*16
__device__ __forceinline__ void gload_lds16(const unsigned short* g, unsigned short* l){
    __builtin_amdgcn_global_load_lds(
        (const __attribute__((address_space(1))) void*)g,
        (__attribute__((address_space(3))) void*)l, 16, 0, 0);
}

// ---- McT = out_w @ wv (folded), bc = out_w @ bv + out_b  (verified r1-r10) ----
__global__ void fold_proj_kernel(const float* __restrict__ in_proj_w,
                                 const float* __restrict__ in_proj_b,
                                 const float* __restrict__ out_w,
                                 const float* __restrict__ out_b,
                                 float* __restrict__ McT,
                                 float* __restrict__ bc)
{
    const int i = blockIdx.x;   // k index
    const int j = threadIdx.x;  // n index
    float acc = 0.f;
    for (int k = 0; k < Hd; ++k)
        acc = fmaf(out_w[j * Hd + k], in_proj_w[(2 * Hd + k) * Hd + i], acc);
    McT[i * Hd + j] = acc;
    if (i == 0){
        float b = out_b[j];
        for (int k = 0; k < Hd; ++k)
            b = fmaf(out_w[j * Hd + k], in_proj_b[2 * Hd + k], b);
        bc[j] = b;
    }
}

// ---- quantize weights to bf16 MFMA B-fragments (verified r4-r10) ----
// frag elem j of lane l at (mat,kc,nc):  W[kc*32 + (l>>4)*8 + j][nc*16 + (l&15)]
__global__ void pack_kernel(const float* __restrict__ r_whh, const float* __restrict__ u_whh,
                            const float* __restrict__ r_wxh, const float* __restrict__ u_wxh,
                            const float* __restrict__ c_whh, const float* __restrict__ c_wxh,
                            const float* __restrict__ McT,
                            unsigned short* __restrict__ whi)
{
    const int mat  = blockIdx.y;   // 0..6
    const int tile = blockIdx.x;   // 0..31 : kc = tile>>3, nc = tile&7
    const int l    = threadIdx.x;  // 0..63
    const float* W;
    switch (mat){
        case 0: W = r_whh; break;  case 1: W = u_whh; break;
        case 2: W = r_wxh; break;  case 3: W = u_wxh; break;
        case 4: W = c_whh; break;  case 5: W = c_wxh; break;
        default: W = McT;
    }
    const int kc = tile >> 3, nc = tile & 7;
    const int kbase = kc * 32 + (l >> 4) * 8;
    const int n = nc * 16 + (l & 15);
    const size_t obase = ((size_t)(mat * 32 + tile) * 64 + l) * 8;
    #pragma unroll
    for (int j = 0; j < 8; ++j)
        whi[obase + j] = f2bf(W[(kbase + j) * Hd + n]);
}

// B-frag read from LDS weight buffer (ds_read_b128, contiguous per wave)
#define BF_LDS(kc, nc) (*(const s16x8*)&WL[(((kc) * 8 + (nc)) * 64 + l) * 8])

#define MM1(acc, AH, BH)                                                  \
    acc = __builtin_amdgcn_mfma_f32_16x16x32_bf16(AH, BH, acc, 0, 0, 0);

__global__ __launch_bounds__(256, 1) void gru_mfma_kernel(
    const float* __restrict__ x_rank,
    const int* __restrict__ valid_idx, int nv,
    const float* __restrict__ r_b, const float* __restrict__ u_b, const float* __restrict__ c_b,
    const unsigned short* __restrict__ whi,
    const float* __restrict__ bc,
    float* __restrict__ out, int N)
{
    // single-buffered block-shared weight stage (32 KB); cross-BLOCK overlap
    // (2 co-resident blocks per CU, independent barrier domains) hides the fill.
    __shared__ __align__(16) unsigned short WL[16384];
    // per-wave bf16 scratch: rh -> h' -> out staging (A-frag-precision anyway)
    __shared__ __align__(16) unsigned short Sr_all[NW][NPW][SRP];
    __shared__ float bias_s[4][Hd];
    __shared__ int lo_all[NW][NPW];
    __shared__ int hi_all[NW][NPW];

    const int tid = threadIdx.x;
    const int wid = tid >> 6;
    const int l   = tid & 63;
    const int lr  = l & 15;
    const int lg  = l >> 4;
    const int n0  = (blockIdx.x * NW + wid) * NPW;

    unsigned short (*Sr)[SRP] = Sr_all[wid];
    int* loL = lo_all[wid];
    int* hiL = hi_all[wid];

    if (tid < Hd){
        bias_s[0][tid] = r_b[tid];
        bias_s[1][tid] = u_b[tid];
        bias_s[2][tid] = c_b[tid];
        bias_s[3][tid] = bc[tid];
    }

    // stage one 32KB matrix: 32 chunks of 1KB; wave covers chunks it*4+wid
    #define STAGE_MAT(mat)                                                       \
        {                                                                        \
            const unsigned short* msrc = whi + (size_t)(mat) * 16384;            \
            _Pragma("unroll")                                                    \
            for (int it = 0; it < 8; ++it){                                      \
                const int chunk = it * 4 + wid;                                  \
                gload_lds16(msrc + chunk * 512 + l * 8, &WL[chunk * 512]);       \
            }                                                                    \
        }

    // persistent register state
    f32x4 hD[8];              // h f32 in D-layout: row lg*4+i, col nc*16+lr
    s16x8 ah[4];              // h A-frags bf16 (row lr, k = kc*32+lg*8+j); h(t=0)=0
    #pragma unroll
    for (int nc = 0; nc < 8; ++nc) hD[nc] = (f32x4){0.f, 0.f, 0.f, 0.f};
    #pragma unroll
    for (int kc = 0; kc < 4; ++kc) ah[kc] = (s16x8)0;
    s16x8 xh[4], rhh[4];

    STAGE_MAT(0);             // prologue: r_whh

    #pragma unroll 1
    for (int t = 0; t < Rr; ++t){
        // ---- output-row ranges (overlaps in-flight staging) ----
        if (l < NPW){
            int n = n0 + l, lo = 0, hi = 0;
            if (n < N){
                int F = (n * Rr + t) * Ll;
                lo = lower_bound_i32(valid_idx, nv, F);
                hi = lower_bound_i32(valid_idx, nv, F + Ll);
            }
            loL[l] = lo; hiL[l] = hi;
        }
        // ---- x A-frags (clamped; OOB rows never stored) ----
        {
            int nn = n0 + lr; if (nn > N - 1) nn = N - 1;
            const float* xp = x_rank + ((size_t)nn * Rr + t) * Hd;
            #pragma unroll
            for (int kc = 0; kc < 4; ++kc)
                xh[kc] = cvt8(xp + kc * 32 + lg * 8);
        }

        f32x4 accR[8], accZ[8];

        // ==== S1: r_whh -> accR = h @ W ====
        __syncthreads();                       // drain staged loads (vmcnt0 + join)
        #pragma unroll
        for (int nc = 0; nc < 8; ++nc){
            accR[nc] = (f32x4){0.f, 0.f, 0.f, 0.f};
            #pragma unroll
            for (int kc = 0; kc < 4; ++kc){ s16x8 b = BF_LDS(kc, nc); MM1(accR[nc], ah[kc], b); }
            if ((nc & 3) == 3) __builtin_amdgcn_sched_barrier(0);
        }
        __syncthreads();                       // readers done
        STAGE_MAT(2);

        // ==== S2: r_wxh -> accR += x @ W ; Sr = bf16(r * h) ====
        __syncthreads();
        #pragma unroll
        for (int nc = 0; nc < 8; ++nc){
            #pragma unroll
            for (int kc = 0; kc < 4; ++kc){ s16x8 b = BF_LDS(kc, nc); MM1(accR[nc], xh[kc], b); }
            const float rbc = bias_s[0][nc * 16 + lr];
            #pragma unroll
            for (int i = 0; i < 4; ++i){
                float r = 1.f / (1.f + __expf(-(accR[nc][i] + rbc)));
                Sr[lg * 4 + i][nc * 16 + lr] = f2bf(r * hD[nc][i]);
            }
            if ((nc & 3) == 3) __builtin_amdgcn_sched_barrier(0);
        }
        __syncthreads();
        STAGE_MAT(1);

        // ==== S3: u_whh -> accZ = h @ W ====
        __syncthreads();
        #pragma unroll
        for (int nc = 0; nc < 8; ++nc){
            accZ[nc] = (f32x4){0.f, 0.f, 0.f, 0.f};
            #pragma unroll
            for (int kc = 0; kc < 4; ++kc){ s16x8 b = BF_LDS(kc, nc); MM1(accZ[nc], ah[kc], b); }
            if ((nc & 3) == 3) __builtin_amdgcn_sched_barrier(0);
        }
        __syncthreads();
        STAGE_MAT(3);

        // ==== S4: u_wxh -> accZ += x @ W ; z = sigmoid (stays in regs) ====
        __syncthreads();
        #pragma unroll
        for (int nc = 0; nc < 8; ++nc){
            #pragma unroll
            for (int kc = 0; kc < 4; ++kc){ s16x8 b = BF_LDS(kc, nc); MM1(accZ[nc], xh[kc], b); }
            const float ubc = bias_s[1][nc * 16 + lr];
            #pragma unroll
            for (int i = 0; i < 4; ++i)
                accZ[nc][i] = 1.f / (1.f + __expf(-(accZ[nc][i] + ubc)));
            if ((nc & 3) == 3) __builtin_amdgcn_sched_barrier(0);
        }
        __syncthreads();
        STAGE_MAT(4);

        // ==== S5: c_whh -> accC = (r*h) @ W  (rh frags direct from bf16 Sr) ====
        __syncthreads();
        #pragma unroll
        for (int kc = 0; kc < 4; ++kc)
            rhh[kc] = *(const s16x8*)&Sr[lr][kc * 32 + lg * 8];
        f32x4 accC[8];
        #pragma unroll
        for (int nc = 0; nc < 8; ++nc){
            accC[nc] = (f32x4){0.f, 0.f, 0.f, 0.f};
            #pragma unroll
            for (int kc = 0; kc < 4; ++kc){ s16x8 b = BF_LDS(kc, nc); MM1(accC[nc], rhh[kc], b); }
            if ((nc & 3) == 3) __builtin_amdgcn_sched_barrier(0);
        }
        __syncthreads();
        STAGE_MAT(5);

        // ==== S6: c_wxh -> accC += x @ W ; h' = h + z*(tanh-h) ; Sr = bf16(h') ====
        __syncthreads();
        #pragma unroll
        for (int nc = 0; nc < 8; ++nc){
            #pragma unroll
            for (int kc = 0; kc < 4; ++kc){ s16x8 b = BF_LDS(kc, nc); MM1(accC[nc], xh[kc], b); }
            const float cbc = bias_s[2][nc * 16 + lr];
            #pragma unroll
            for (int i = 0; i < 4; ++i){
                float e = __expf(2.f * (accC[nc][i] + cbc));
                float c = 1.f - 2.f / (e + 1.f);     // tanh, saturates correctly
                float ho = hD[nc][i];
                float hn = ho + accZ[nc][i] * (c - ho);
                hD[nc][i] = hn;
                Sr[lg * 4 + i][nc * 16 + lr] = f2bf(hn);
            }
            if ((nc & 3) == 3) __builtin_amdgcn_sched_barrier(0);
        }
        // h' A-frags: serve S7 now AND S1 of next t (same-wave LDS in-order)
        #pragma unroll
        for (int kc = 0; kc < 4; ++kc)
            ah[kc] = *(const s16x8*)&Sr[lr][kc * 32 + lg * 8];
        __syncthreads();
        STAGE_MAT(6);

        // ==== S7: McT -> o ; Sr = bf16(o) ; stage next r_whh ; epilogue ====
        __syncthreads();
        #pragma unroll
        for (int nc = 0; nc < 8; ++nc){
            f32x4 ao = (f32x4){0.f, 0.f, 0.f, 0.f};
            #pragma unroll
            for (int kc = 0; kc < 4; ++kc){ s16x8 b = BF_LDS(kc, nc); MM1(ao, ah[kc], b); }
            const float obc = bias_s[3][nc * 16 + lr];
            #pragma unroll
            for (int i = 0; i < 4; ++i)
                Sr[lg * 4 + i][nc * 16 + lr] = f2bf(ao[i] + obc);
            if ((nc & 3) == 3) __builtin_amdgcn_sched_barrier(0);
        }
        __syncthreads();                      // WL readers done
        if (t < Rr - 1) STAGE_MAT(0);         // overlap next stage with epilogue

        // epilogue: 32 lanes cover one 512-B out row; own-wave Sr (no barrier)
        #pragma unroll
        for (int m = 0; m < 8; ++m){
            const int row = m * 2 + (l >> 5);
            const int c4  = (l & 31) * 4;
            const uint2 u = *(const uint2*)&Sr[row][c4];
            float4 v = { bf2f((unsigned short)(u.x & 0xffff)),
                         bf2f((unsigned short)(u.x >> 16)),
                         bf2f((unsigned short)(u.y & 0xffff)),
                         bf2f((unsigned short)(u.y >> 16)) };
            const int lo = loL[row], hi = hiL[row];
            for (int rr = lo; rr < hi; ++rr)
                *(float4*)(out + (size_t)rr * Hd + c4) = v;
        }
    }
    #undef STAGE_MAT
}

__global__ void he_order_kernel(const int* __restrict__ he_order,
                                float* __restrict__ out_tail, int nv)
{
    const int i = blockIdx.x * 256 + threadIdx.x;
    if (i < nv) out_tail[i] = (float)he_order[i];
}

extern "C" void kernel_launch(void* const* d_in, const int* in_sizes, int n_in,
                              void* d_out, int out_size, void* d_ws, size_t ws_size,
                              hipStream_t stream)
{
    const float* x_rank    = (const float*)d_in[0];
    // d_in[1] he_features, d_in[2] he_idx: dead (softmax over singleton axis == 1)
    const int*   valid_idx = (const int*)d_in[3];
    const int*   he_order  = (const int*)d_in[4];
    const float* r_whh = (const float*)d_in[5];
    const float* r_wxh = (const float*)d_in[6];
    const float* r_b   = (const float*)d_in[7];
    const float* u_whh = (const float*)d_in[8];
    const float* u_wxh = (const float*)d_in[9];
    const float* u_b   = (const float*)d_in[10];
    const float* c_whh = (const float*)d_in[11];
    const float* c_wxh = (const float*)d_in[12];
    const float* c_b   = (const float*)d_in[13];
    const float* in_proj_w = (const float*)d_in[14];
    const float* in_proj_b = (const float*)d_in[15];
    const float* out_w     = (const float*)d_in[16];
    const float* out_b     = (const float*)d_in[17];

    const int nv = in_sizes[3];
    const int N  = in_sizes[0] / (Rr * Hd);

    // workspace layout
    float* McT = (float*)d_ws;                         // 16384 f32
    float* bc  = McT + Hd * Hd;                        // 128 f32
    unsigned short* whi = (unsigned short*)(bc + Hd);  // 7*16384 u16

    float* out_f    = (float*)d_out;
    float* out_tail = out_f + (size_t)nv * Hd;

    fold_proj_kernel<<<Hd, Hd, 0, stream>>>(in_proj_w, in_proj_b, out_w, out_b, McT, bc);
    pack_kernel<<<dim3(32, 7), 64, 0, stream>>>(r_whh, u_whh, r_wxh, u_wxh, c_whh, c_wxh,
                                                McT, whi);

    const int nodes_per_block = NW * NPW;  // 64
    const int nblocks = (N + nodes_per_block - 1) / nodes_per_block;  // 469
    gru_mfma_kernel<<<nblocks, 256, 0, stream>>>(
        x_rank, valid_idx, nv, r_b, u_b, c_b, whi, bc, out_f, N);

    he_order_kernel<<<(nv + 255) / 256, 256, 0, stream>>>(he_order, out_tail, nv);
}